// Round 13
// baseline (304.576 us; speedup 1.0000x reference)
//
#include <hip/hip_runtime.h>

#define NS    88     // species
#define CCH   128    // channels
#define BCAP  16384  // per-species bucket capacity
#define STR   20     // stripe blocks per species (16 atoms each; grid-stride if more)

typedef float f32x4 __attribute__((ext_vector_type(4)));

__device__ const int TRI[20][3] = {
    {0,0,0},{0,0,1},{0,0,2},{0,0,3},{0,1,1},{0,1,2},{0,1,3},{0,2,2},{0,2,3},{0,3,3},
    {1,1,1},{1,1,2},{1,1,3},{1,2,2},{1,2,3},{1,3,3},
    {2,2,2},{2,2,3},{2,3,3},
    {3,3,3}};
__device__ const int PAIR[10][2] = {
    {0,0},{0,1},{0,2},{0,3},{1,1},{1,2},{1,3},{2,2},{2,3},{3,3}};

// ---------------- fused setup: blocks 0..87 sort, 88..98 coef table ----------------
// Sort (R12-verified): block s compacts its species bucket, ascending, atomic-free.
// Table (R11-verified): T[s][m(34)][c(128)][4]; m: 0..19 cubic (TRI), 20..29 pairs,
// 30..33 linear; comp[0]=0e, [1..3]=1o.

__global__ __launch_bounds__(1024) void k_setup(
    const int* __restrict__ species, int N,
    const float* __restrict__ u1_0e, const float* __restrict__ w1_0e,
    const float* __restrict__ u1_1o, const float* __restrict__ w1_1o,
    const float* __restrict__ u2_0e, const float* __restrict__ w2_0e,
    const float* __restrict__ u2_1o, const float* __restrict__ w2_1o,
    const float* __restrict__ u3_0e, const float* __restrict__ w3_0e,
    const float* __restrict__ u3_1o, const float* __restrict__ w3_1o,
    float* __restrict__ T, int* __restrict__ counts, int* __restrict__ list) {

    __shared__ int wh[16];
    __shared__ float S3e[20][4];
    __shared__ float S3o[20][6][3];
    __shared__ float S2e[10][2];
    __shared__ float S2o[10][2][3];
    __shared__ float S1e[4];
    __shared__ float S1o[4][3];

    int tid = threadIdx.x;

    if (blockIdx.x < NS) {
        int s = blockIdx.x;
        int lane = tid & 63, w = tid >> 6;
        int* bucket = list + s * BCAP;
        int pos = 0;
        for (int base = 0; base < N; base += 1024) {
            int n = base + tid;
            bool m = (n < N) && (species[n] == s);
            unsigned long long b = __ballot(m);
            int rank = __popcll(b & ((1ull << lane) - 1));
            if (lane == 0) wh[w] = __popcll(b);
            __syncthreads();
            int wbase = 0, tot = 0;
#pragma unroll
            for (int i = 0; i < 16; ++i) { int v = wh[i]; if (i < w) wbase += v; tot += v; }
            if (m) bucket[pos + wbase + rank] = n;
            pos += tot;
            __syncthreads();
        }
        if (tid == 0) counts[s] = pos;
        return;
    }

    // ---- stage A: symmetrized bases into LDS (536 jobs) ----
    for (int j = tid; j < 536; j += 1024) {
        if (j < 80) {
            int m = j >> 2, k = j & 3;
            int a = TRI[m][0], b = TRI[m][1], d = TRI[m][2];
            int P[6][3] = {{a,b,d},{a,d,b},{b,a,d},{b,d,a},{d,a,b},{d,b,a}};
            float acc = 0.f;
#pragma unroll
            for (int p = 0; p < 6; ++p)
                acc += u3_0e[((P[p][0] * 4 + P[p][1]) * 4 + P[p][2]) * 4 + k];
            float inv = (a == d) ? (1.f / 6.f) : ((a == b || b == d) ? 0.5f : 1.f);
            S3e[m][k] = acc * inv;
        } else if (j < 440) {
            int r = j - 80;
            int m = r / 18, jj = r % 18, k = jj / 3, i = jj % 3;
            int a = TRI[m][0], b = TRI[m][1], d = TRI[m][2];
            int P[6][3] = {{a,b,d},{a,d,b},{b,a,d},{b,d,a},{d,a,b},{d,b,a}};
            float acc = 0.f;
#pragma unroll
            for (int p = 0; p < 6; ++p)
                acc += u3_1o[(((P[p][0] * 4 + P[p][1]) * 4 + P[p][2]) * 6 + k) * 3 + i];
            float inv = (a == d) ? (1.f / 6.f) : ((a == b || b == d) ? 0.5f : 1.f);
            S3o[m][k][i] = acc * inv;
        } else if (j < 460) {
            int r = j - 440;
            int m = r >> 1, k = r & 1;
            int a = PAIR[m][0], b = PAIR[m][1];
            float acc = u2_0e[(a * 4 + b) * 2 + k];
            if (a != b) acc += u2_0e[(b * 4 + a) * 2 + k];
            S2e[m][k] = acc;
        } else if (j < 520) {
            int r = j - 460;
            int m = r / 6, jj = r % 6, k = jj / 3, i = jj % 3;
            int a = PAIR[m][0], b = PAIR[m][1];
            float acc = u2_1o[((a * 4 + b) * 2 + k) * 3 + i];
            if (a != b) acc += u2_1o[((b * 4 + a) * 2 + k) * 3 + i];
            S2o[m][k][i] = acc;
        } else if (j < 524) {
            int d = j - 520;
            S1e[d] = u1_0e[d];
        } else {
            int r = j - 524;
            S1o[r / 3][r % 3] = u1_1o[r];
        }
    }
    __syncthreads();

    // ---- stage B: per (s,c) contraction with weights -> T rows ----
    int tg = (blockIdx.x - NS) * 1024 + tid;             // 11*1024 = 88*128
    int s = tg >> 7, c = tg & 127;

    float wk3e[4], wk3o[6], wk2e[2], wk2o[2];
#pragma unroll
    for (int k = 0; k < 4; ++k) wk3e[k] = w3_0e[(s * 4 + k) * CCH + c];
#pragma unroll
    for (int k = 0; k < 6; ++k) wk3o[k] = w3_1o[(s * 6 + k) * CCH + c];
#pragma unroll
    for (int k = 0; k < 2; ++k) wk2e[k] = w2_0e[(s * 2 + k) * CCH + c];
#pragma unroll
    for (int k = 0; k < 2; ++k) wk2o[k] = w2_1o[(s * 2 + k) * CCH + c];
    float wk1e = w1_0e[s * CCH + c];
    float wk1o = w1_1o[s * CCH + c];

    f32x4* Trow = reinterpret_cast<f32x4*>(T) + (size_t)s * 34 * CCH + c;
#pragma unroll
    for (int m = 0; m < 20; ++m) {
        f32x4 row;
        float e = 0.f;
#pragma unroll
        for (int k = 0; k < 4; ++k) e = fmaf(S3e[m][k], wk3e[k], e);
        row.x = e;
#pragma unroll
        for (int i = 0; i < 3; ++i) {
            float o = 0.f;
#pragma unroll
            for (int k = 0; k < 6; ++k) o = fmaf(S3o[m][k][i], wk3o[k], o);
            row[1 + i] = o;
        }
        Trow[m * CCH] = row;
    }
#pragma unroll
    for (int m = 0; m < 10; ++m) {
        f32x4 row;
        row.x = fmaf(S2e[m][0], wk2e[0], S2e[m][1] * wk2e[1]);
#pragma unroll
        for (int i = 0; i < 3; ++i)
            row[1 + i] = fmaf(S2o[m][0][i], wk2o[0], S2o[m][1][i] * wk2o[1]);
        Trow[(20 + m) * CCH] = row;
    }
#pragma unroll
    for (int d = 0; d < 4; ++d) {
        f32x4 row;
        row.x = S1e[d] * wk1e;
#pragma unroll
        for (int i = 0; i < 3; ++i) row[1 + i] = S1o[d][i] * wk1o;
        Trow[(30 + d) * CCH] = row;
    }
}

// ---------------- main kernel: occupancy-first, coef direct from L2 ----------------
// Grid (NS, STR), block 256 = 4 waves. Wave w: atom-group grp=w>>1 (8 atoms),
// channel half g=w&1; lane = channel c64. Per m: one coalesced 1KB f32x4 coef
// load from T (L2-resident) serves 8 atoms x 4 comps. 7040 waves -> TLP hides
// all load latency; no LDS, no per-block preamble.

__global__ __launch_bounds__(256, 3) void k_main(
    const float* __restrict__ x, const float* __restrict__ T,
    const int* __restrict__ list, const int* __restrict__ counts,
    float* __restrict__ out) {
    int s = blockIdx.x;
    int cnt = counts[s];
    if (cnt == 0) return;
    int tid = threadIdx.x;
    int lane = tid & 63, w = tid >> 6;
    int grp = w >> 1, g = w & 1;
    int cg = g * 64 + lane;
    const int* bucket = list + s * BCAP;
    const f32x4* Tm = reinterpret_cast<const f32x4*>(T) + (size_t)s * 34 * CCH + cg;

    constexpr int A3[20] = {0,0,0,0,0,0,0,0,0,0,1,1,1,1,1,1,2,2,2,3};
    constexpr int B3[20] = {0,0,0,0,1,1,1,2,2,3,1,1,1,2,2,3,2,2,3,3};
    constexpr int D3[20] = {0,1,2,3,1,2,3,2,3,3,1,2,3,2,3,3,2,3,3,3};
    constexpr int A2[10] = {0,0,0,0,1,1,1,2,2,3};
    constexpr int B2[10] = {0,1,2,3,1,2,3,2,3,3};

    for (int t0 = (int)blockIdx.y * 16; t0 < cnt; t0 += STR * 16) {
        int base = t0 + grp * 8;
        if (base >= cnt) continue;

        int nn[8];
        f32x4 xr[8];
#pragma unroll
        for (int j = 0; j < 8; ++j) {
            int p = base + j;
            nn[j] = bucket[p < cnt ? p : cnt - 1];
            xr[j] = *reinterpret_cast<const f32x4*>(x + (size_t)nn[j] * 512 + cg * 4);
        }

        float acc[8][4];
#pragma unroll
        for (int j = 0; j < 8; ++j)
#pragma unroll
            for (int k = 0; k < 4; ++k) acc[j][k] = 0.f;

#pragma unroll
        for (int m = 0; m < 34; ++m) {
            f32x4 cf = Tm[m * CCH];
#pragma unroll
            for (int j = 0; j < 8; ++j) {
                float mono;
                if (m < 20)      mono = xr[j][A3[m]] * xr[j][B3[m]] * xr[j][D3[m]];
                else if (m < 30) mono = xr[j][A2[m - 20]] * xr[j][B2[m - 20]];
                else             mono = xr[j][m - 30];
                acc[j][0] = fmaf(cf[0], mono, acc[j][0]);
                acc[j][1] = fmaf(cf[1], mono, acc[j][1]);
                acc[j][2] = fmaf(cf[2], mono, acc[j][2]);
                acc[j][3] = fmaf(cf[3], mono, acc[j][3]);
            }
        }

#pragma unroll
        for (int j = 0; j < 8; ++j) {
            if (base + j < cnt) {
                float* orow = out + (size_t)nn[j] * 512;
                orow[cg] = acc[j][0];
                orow[CCH + 3 * cg + 0] = acc[j][1];
                orow[CCH + 3 * cg + 1] = acc[j][2];
                orow[CCH + 3 * cg + 2] = acc[j][3];
            }
        }
    }
}

// ---------------- launch ----------------

extern "C" void kernel_launch(void* const* d_in, const int* in_sizes, int n_in,
                              void* d_out, int out_size, void* d_ws, size_t ws_size,
                              hipStream_t stream) {
    const float* x     = (const float*)d_in[0];
    const float* u1_0e = (const float*)d_in[1];
    const float* w1_0e = (const float*)d_in[2];
    const float* u1_1o = (const float*)d_in[3];
    const float* w1_1o = (const float*)d_in[4];
    const float* u2_0e = (const float*)d_in[5];
    const float* w2_0e = (const float*)d_in[6];
    const float* u2_1o = (const float*)d_in[7];
    const float* w2_1o = (const float*)d_in[8];
    const float* u3_0e = (const float*)d_in[9];
    const float* w3_0e = (const float*)d_in[10];
    const float* u3_1o = (const float*)d_in[11];
    const float* w3_1o = (const float*)d_in[12];
    const int*   spec  = (const int*)d_in[13];
    int N = in_sizes[13];
    float* out = (float*)d_out;

    char* ws = (char*)d_ws;
    float* T      = (float*)ws;                              // NS*34*CCH*4 floats (6.13 MB)
    size_t tbytes = (size_t)NS * 34 * CCH * 4 * sizeof(float);
    int* list     = (int*)(ws + tbytes);                     // NS*BCAP ints
    int* counts   = list + (size_t)NS * BCAP;                // NS ints

    k_setup<<<NS + 11, 1024, 0, stream>>>(
        spec, N,
        u1_0e, w1_0e, u1_1o, w1_1o,
        u2_0e, w2_0e, u2_1o, w2_1o,
        u3_0e, w3_0e, u3_1o, w3_1o,
        T, counts, list);
    k_main<<<dim3(NS, STR), 256, 0, stream>>>(x, T, list, counts, out);
}

// Round 14
// 198.159 us; speedup vs baseline: 1.5370x; 1.5370x over previous
//
#include <hip/hip_runtime.h>

#define NS    88     // species
#define CCH   128    // channels
#define BCAP  16384  // per-species bucket capacity
#define STR   16     // stripe blocks per species (16 atoms each; grid-stride beyond)

typedef float f32x4 __attribute__((ext_vector_type(4)));

__device__ const int TRI[20][3] = {
    {0,0,0},{0,0,1},{0,0,2},{0,0,3},{0,1,1},{0,1,2},{0,1,3},{0,2,2},{0,2,3},{0,3,3},
    {1,1,1},{1,1,2},{1,1,3},{1,2,2},{1,2,3},{1,3,3},
    {2,2,2},{2,2,3},{2,3,3},
    {3,3,3}};
__device__ const int PAIR[10][2] = {
    {0,0},{0,1},{0,2},{0,3},{1,1},{1,2},{1,3},{2,2},{2,3},{3,3}};

// ---------------- fused setup: blocks 0..87 sort, 88..98 coef table (R13-verified) ----------------
// T[s][m(34)][c(128)][4]; m: 0..19 cubic (TRI), 20..29 pairs, 30..33 linear; comp[0]=0e,[1..3]=1o.

__global__ __launch_bounds__(1024) void k_setup(
    const int* __restrict__ species, int N,
    const float* __restrict__ u1_0e, const float* __restrict__ w1_0e,
    const float* __restrict__ u1_1o, const float* __restrict__ w1_1o,
    const float* __restrict__ u2_0e, const float* __restrict__ w2_0e,
    const float* __restrict__ u2_1o, const float* __restrict__ w2_1o,
    const float* __restrict__ u3_0e, const float* __restrict__ w3_0e,
    const float* __restrict__ u3_1o, const float* __restrict__ w3_1o,
    float* __restrict__ T, int* __restrict__ counts, int* __restrict__ list) {

    __shared__ int wh[16];
    __shared__ float S3e[20][4];
    __shared__ float S3o[20][6][3];
    __shared__ float S2e[10][2];
    __shared__ float S2o[10][2][3];
    __shared__ float S1e[4];
    __shared__ float S1o[4][3];

    int tid = threadIdx.x;

    if (blockIdx.x < NS) {
        int s = blockIdx.x;
        int lane = tid & 63, w = tid >> 6;
        int* bucket = list + s * BCAP;
        int pos = 0;
        for (int base = 0; base < N; base += 1024) {
            int n = base + tid;
            bool m = (n < N) && (species[n] == s);
            unsigned long long b = __ballot(m);
            int rank = __popcll(b & ((1ull << lane) - 1));
            if (lane == 0) wh[w] = __popcll(b);
            __syncthreads();
            int wbase = 0, tot = 0;
#pragma unroll
            for (int i = 0; i < 16; ++i) { int v = wh[i]; if (i < w) wbase += v; tot += v; }
            if (m) bucket[pos + wbase + rank] = n;
            pos += tot;
            __syncthreads();
        }
        if (tid == 0) counts[s] = pos;
        return;
    }

    // ---- stage A: symmetrized bases into LDS (536 jobs) ----
    for (int j = tid; j < 536; j += 1024) {
        if (j < 80) {
            int m = j >> 2, k = j & 3;
            int a = TRI[m][0], b = TRI[m][1], d = TRI[m][2];
            int P[6][3] = {{a,b,d},{a,d,b},{b,a,d},{b,d,a},{d,a,b},{d,b,a}};
            float acc = 0.f;
#pragma unroll
            for (int p = 0; p < 6; ++p)
                acc += u3_0e[((P[p][0] * 4 + P[p][1]) * 4 + P[p][2]) * 4 + k];
            float inv = (a == d) ? (1.f / 6.f) : ((a == b || b == d) ? 0.5f : 1.f);
            S3e[m][k] = acc * inv;
        } else if (j < 440) {
            int r = j - 80;
            int m = r / 18, jj = r % 18, k = jj / 3, i = jj % 3;
            int a = TRI[m][0], b = TRI[m][1], d = TRI[m][2];
            int P[6][3] = {{a,b,d},{a,d,b},{b,a,d},{b,d,a},{d,a,b},{d,b,a}};
            float acc = 0.f;
#pragma unroll
            for (int p = 0; p < 6; ++p)
                acc += u3_1o[(((P[p][0] * 4 + P[p][1]) * 4 + P[p][2]) * 6 + k) * 3 + i];
            float inv = (a == d) ? (1.f / 6.f) : ((a == b || b == d) ? 0.5f : 1.f);
            S3o[m][k][i] = acc * inv;
        } else if (j < 460) {
            int r = j - 440;
            int m = r >> 1, k = r & 1;
            int a = PAIR[m][0], b = PAIR[m][1];
            float acc = u2_0e[(a * 4 + b) * 2 + k];
            if (a != b) acc += u2_0e[(b * 4 + a) * 2 + k];
            S2e[m][k] = acc;
        } else if (j < 520) {
            int r = j - 460;
            int m = r / 6, jj = r % 6, k = jj / 3, i = jj % 3;
            int a = PAIR[m][0], b = PAIR[m][1];
            float acc = u2_1o[((a * 4 + b) * 2 + k) * 3 + i];
            if (a != b) acc += u2_1o[((b * 4 + a) * 2 + k) * 3 + i];
            S2o[m][k][i] = acc;
        } else if (j < 524) {
            int d = j - 520;
            S1e[d] = u1_0e[d];
        } else {
            int r = j - 524;
            S1o[r / 3][r % 3] = u1_1o[r];
        }
    }
    __syncthreads();

    // ---- stage B: per (s,c) contraction with weights -> T rows ----
    int tg = (blockIdx.x - NS) * 1024 + tid;             // 11*1024 = 88*128
    int s = tg >> 7, c = tg & 127;

    float wk3e[4], wk3o[6], wk2e[2], wk2o[2];
#pragma unroll
    for (int k = 0; k < 4; ++k) wk3e[k] = w3_0e[(s * 4 + k) * CCH + c];
#pragma unroll
    for (int k = 0; k < 6; ++k) wk3o[k] = w3_1o[(s * 6 + k) * CCH + c];
#pragma unroll
    for (int k = 0; k < 2; ++k) wk2e[k] = w2_0e[(s * 2 + k) * CCH + c];
#pragma unroll
    for (int k = 0; k < 2; ++k) wk2o[k] = w2_1o[(s * 2 + k) * CCH + c];
    float wk1e = w1_0e[s * CCH + c];
    float wk1o = w1_1o[s * CCH + c];

    f32x4* Trow = reinterpret_cast<f32x4*>(T) + (size_t)s * 34 * CCH + c;
#pragma unroll
    for (int m = 0; m < 20; ++m) {
        f32x4 row;
        float e = 0.f;
#pragma unroll
        for (int k = 0; k < 4; ++k) e = fmaf(S3e[m][k], wk3e[k], e);
        row.x = e;
#pragma unroll
        for (int i = 0; i < 3; ++i) {
            float o = 0.f;
#pragma unroll
            for (int k = 0; k < 6; ++k) o = fmaf(S3o[m][k][i], wk3o[k], o);
            row[1 + i] = o;
        }
        Trow[m * CCH] = row;
    }
#pragma unroll
    for (int m = 0; m < 10; ++m) {
        f32x4 row;
        row.x = fmaf(S2e[m][0], wk2e[0], S2e[m][1] * wk2e[1]);
#pragma unroll
        for (int i = 0; i < 3; ++i)
            row[1 + i] = fmaf(S2o[m][0][i], wk2o[0], S2o[m][1][i] * wk2o[1]);
        Trow[(20 + m) * CCH] = row;
    }
#pragma unroll
    for (int d = 0; d < 4; ++d) {
        f32x4 row;
        row.x = S1e[d] * wk1e;
#pragma unroll
        for (int i = 0; i < 3; ++i) row[1 + i] = S1o[d][i] * wk1o;
        Trow[(30 + d) * CCH] = row;
    }
}

// ---------------- main kernel: high occupancy, small state, LDS coefs ----------------
// Grid (NS, STR, 2): species, 16-atom stripe, channel half g. Block 256 = 4 waves,
// ALL on half g: lane = c64, wave grp owns 4 atoms (block = 16 atoms x 64 channels).
// LDS: coefs[34][64][4] = 34.8 KB staged by coalesced memcpy from T -> 4 blocks/CU,
// 16 waves/CU; ~8400 waves total (4/SIMD). Per-thread live state ~55 VGPR (no spill
// even under a conservative allocator -- R13 lesson).

__global__ __launch_bounds__(256, 4) void k_main(
    const float* __restrict__ x, const float* __restrict__ T,
    const int* __restrict__ list, const int* __restrict__ counts,
    float* __restrict__ out) {
    int s = blockIdx.x;
    int cnt = counts[s];
    if ((int)blockIdx.y * 16 >= cnt) return;    // block-uniform
    int g = blockIdx.z;
    int tid = threadIdx.x;
    int c64 = tid & 63, grp = tid >> 6;
    int cg = g * 64 + c64;
    const int* bucket = list + s * BCAP;

    __shared__ float coefs[34 * 64 * 4];        // 34,816 B
    __shared__ int bidx[16];

    // stage coef slice (coalesced 1KB runs from T, L2/L3-resident)
    {
        const f32x4* gsrc = reinterpret_cast<const f32x4*>(T) + (size_t)s * 34 * CCH + g * 64;
        f32x4* ldst = reinterpret_cast<f32x4*>(coefs);
        for (int i = tid; i < 34 * 64; i += 256) {
            int m = i >> 6, cc = i & 63;
            ldst[i] = gsrc[(size_t)m * CCH + cc];
        }
    }
    const f32x4* cfs = reinterpret_cast<const f32x4*>(coefs);

    constexpr int A3[20] = {0,0,0,0,0,0,0,0,0,0,1,1,1,1,1,1,2,2,2,3};
    constexpr int B3[20] = {0,0,0,0,1,1,1,2,2,3,1,1,1,2,2,3,2,2,3,3};
    constexpr int D3[20] = {0,1,2,3,1,2,3,2,3,3,1,2,3,2,3,3,2,3,3,3};
    constexpr int A2[10] = {0,0,0,0,1,1,1,2,2,3};
    constexpr int B2[10] = {0,1,2,3,1,2,3,2,3,3};

    for (int t0 = (int)blockIdx.y * 16; t0 < cnt; t0 += STR * 16) {
        if (tid < 16) {
            int tt = t0 + tid;
            bidx[tid] = bucket[tt < cnt ? tt : cnt - 1];
        }
        __syncthreads();
        int nvalid = cnt - t0;

        int nn[4];
        f32x4 xr[4];
#pragma unroll
        for (int j = 0; j < 4; ++j) {
            nn[j] = bidx[grp * 4 + j];
            xr[j] = *reinterpret_cast<const f32x4*>(x + (size_t)nn[j] * 512 + cg * 4);
        }

        float acc[4][4];
#pragma unroll
        for (int j = 0; j < 4; ++j)
#pragma unroll
            for (int k = 0; k < 4; ++k) acc[j][k] = 0.f;

#pragma unroll
        for (int m = 0; m < 34; ++m) {
            f32x4 cf = cfs[m * 64 + c64];
#pragma unroll
            for (int j = 0; j < 4; ++j) {
                float mono;
                if (m < 20)      mono = xr[j][A3[m]] * xr[j][B3[m]] * xr[j][D3[m]];
                else if (m < 30) mono = xr[j][A2[m - 20]] * xr[j][B2[m - 20]];
                else             mono = xr[j][m - 30];
                acc[j][0] = fmaf(cf[0], mono, acc[j][0]);
                acc[j][1] = fmaf(cf[1], mono, acc[j][1]);
                acc[j][2] = fmaf(cf[2], mono, acc[j][2]);
                acc[j][3] = fmaf(cf[3], mono, acc[j][3]);
            }
        }

#pragma unroll
        for (int j = 0; j < 4; ++j) {
            if (grp * 4 + j < nvalid) {
                float* orow = out + (size_t)nn[j] * 512;
                orow[cg] = acc[j][0];
                orow[CCH + 3 * cg + 0] = acc[j][1];
                orow[CCH + 3 * cg + 1] = acc[j][2];
                orow[CCH + 3 * cg + 2] = acc[j][3];
            }
        }
        __syncthreads();
    }
}

// ---------------- launch ----------------

extern "C" void kernel_launch(void* const* d_in, const int* in_sizes, int n_in,
                              void* d_out, int out_size, void* d_ws, size_t ws_size,
                              hipStream_t stream) {
    const float* x     = (const float*)d_in[0];
    const float* u1_0e = (const float*)d_in[1];
    const float* w1_0e = (const float*)d_in[2];
    const float* u1_1o = (const float*)d_in[3];
    const float* w1_1o = (const float*)d_in[4];
    const float* u2_0e = (const float*)d_in[5];
    const float* w2_0e = (const float*)d_in[6];
    const float* u2_1o = (const float*)d_in[7];
    const float* w2_1o = (const float*)d_in[8];
    const float* u3_0e = (const float*)d_in[9];
    const float* w3_0e = (const float*)d_in[10];
    const float* u3_1o = (const float*)d_in[11];
    const float* w3_1o = (const float*)d_in[12];
    const int*   spec  = (const int*)d_in[13];
    int N = in_sizes[13];
    float* out = (float*)d_out;

    char* ws = (char*)d_ws;
    float* T      = (float*)ws;                              // NS*34*CCH*4 floats (6.13 MB)
    size_t tbytes = (size_t)NS * 34 * CCH * 4 * sizeof(float);
    int* list     = (int*)(ws + tbytes);                     // NS*BCAP ints
    int* counts   = list + (size_t)NS * BCAP;                // NS ints

    k_setup<<<NS + 11, 1024, 0, stream>>>(
        spec, N,
        u1_0e, w1_0e, u1_1o, w1_1o,
        u2_0e, w2_0e, u2_1o, w2_1o,
        u3_0e, w3_0e, u3_1o, w3_1o,
        T, counts, list);
    k_main<<<dim3(NS, STR, 2), 256, 0, stream>>>(x, T, list, counts, out);
}

// Round 15
// 46.972 us; speedup vs baseline: 6.4842x; 4.2187x over previous
//
#include <hip/hip_runtime.h>

#define NS    88     // species
#define CCH   128    // channels
#define BCAP  16384  // per-species bucket capacity
#define STR   6      // stripes of AB atoms per species
#define AB    128    // atoms per k_main block

typedef float f32x4 __attribute__((ext_vector_type(4)));

__device__ const int TRI[20][3] = {
    {0,0,0},{0,0,1},{0,0,2},{0,0,3},{0,1,1},{0,1,2},{0,1,3},{0,2,2},{0,2,3},{0,3,3},
    {1,1,1},{1,1,2},{1,1,3},{1,2,2},{1,2,3},{1,3,3},
    {2,2,2},{2,2,3},{2,3,3},
    {3,3,3}};
__device__ const int PAIR[10][2] = {
    {0,0},{0,1},{0,2},{0,3},{1,1},{1,2},{1,3},{2,2},{2,3},{3,3}};

// ---------------- fused setup: blocks 0..87 sort, 88..98 coef table (R13/R14-verified) ----------------
// T[s][m(34)][c(128)][4]; m: 0..19 cubic (TRI), 20..29 pairs, 30..33 linear; comp[0]=0e,[1..3]=1o.

__global__ __launch_bounds__(1024) void k_setup(
    const int* __restrict__ species, int N,
    const float* __restrict__ u1_0e, const float* __restrict__ w1_0e,
    const float* __restrict__ u1_1o, const float* __restrict__ w1_1o,
    const float* __restrict__ u2_0e, const float* __restrict__ w2_0e,
    const float* __restrict__ u2_1o, const float* __restrict__ w2_1o,
    const float* __restrict__ u3_0e, const float* __restrict__ w3_0e,
    const float* __restrict__ u3_1o, const float* __restrict__ w3_1o,
    float* __restrict__ T, int* __restrict__ counts, int* __restrict__ list) {

    __shared__ int wh[16];
    __shared__ float S3e[20][4];
    __shared__ float S3o[20][6][3];
    __shared__ float S2e[10][2];
    __shared__ float S2o[10][2][3];
    __shared__ float S1e[4];
    __shared__ float S1o[4][3];

    int tid = threadIdx.x;

    if (blockIdx.x < NS) {
        int s = blockIdx.x;
        int lane = tid & 63, w = tid >> 6;
        int* bucket = list + s * BCAP;
        int pos = 0;
        for (int base = 0; base < N; base += 1024) {
            int n = base + tid;
            bool m = (n < N) && (species[n] == s);
            unsigned long long b = __ballot(m);
            int rank = __popcll(b & ((1ull << lane) - 1));
            if (lane == 0) wh[w] = __popcll(b);
            __syncthreads();
            int wbase = 0, tot = 0;
#pragma unroll
            for (int i = 0; i < 16; ++i) { int v = wh[i]; if (i < w) wbase += v; tot += v; }
            if (m) bucket[pos + wbase + rank] = n;
            pos += tot;
            __syncthreads();
        }
        if (tid == 0) counts[s] = pos;
        return;
    }

    // ---- stage A: symmetrized bases into LDS (536 jobs) ----
    for (int j = tid; j < 536; j += 1024) {
        if (j < 80) {
            int m = j >> 2, k = j & 3;
            int a = TRI[m][0], b = TRI[m][1], d = TRI[m][2];
            int P[6][3] = {{a,b,d},{a,d,b},{b,a,d},{b,d,a},{d,a,b},{d,b,a}};
            float acc = 0.f;
#pragma unroll
            for (int p = 0; p < 6; ++p)
                acc += u3_0e[((P[p][0] * 4 + P[p][1]) * 4 + P[p][2]) * 4 + k];
            float inv = (a == d) ? (1.f / 6.f) : ((a == b || b == d) ? 0.5f : 1.f);
            S3e[m][k] = acc * inv;
        } else if (j < 440) {
            int r = j - 80;
            int m = r / 18, jj = r % 18, k = jj / 3, i = jj % 3;
            int a = TRI[m][0], b = TRI[m][1], d = TRI[m][2];
            int P[6][3] = {{a,b,d},{a,d,b},{b,a,d},{b,d,a},{d,a,b},{d,b,a}};
            float acc = 0.f;
#pragma unroll
            for (int p = 0; p < 6; ++p)
                acc += u3_1o[(((P[p][0] * 4 + P[p][1]) * 4 + P[p][2]) * 6 + k) * 3 + i];
            float inv = (a == d) ? (1.f / 6.f) : ((a == b || b == d) ? 0.5f : 1.f);
            S3o[m][k][i] = acc * inv;
        } else if (j < 460) {
            int r = j - 440;
            int m = r >> 1, k = r & 1;
            int a = PAIR[m][0], b = PAIR[m][1];
            float acc = u2_0e[(a * 4 + b) * 2 + k];
            if (a != b) acc += u2_0e[(b * 4 + a) * 2 + k];
            S2e[m][k] = acc;
        } else if (j < 520) {
            int r = j - 460;
            int m = r / 6, jj = r % 6, k = jj / 3, i = jj % 3;
            int a = PAIR[m][0], b = PAIR[m][1];
            float acc = u2_1o[((a * 4 + b) * 2 + k) * 3 + i];
            if (a != b) acc += u2_1o[((b * 4 + a) * 2 + k) * 3 + i];
            S2o[m][k][i] = acc;
        } else if (j < 524) {
            int d = j - 520;
            S1e[d] = u1_0e[d];
        } else {
            int r = j - 524;
            S1o[r / 3][r % 3] = u1_1o[r];
        }
    }
    __syncthreads();

    // ---- stage B: per (s,c) contraction with weights -> T rows ----
    int tg = (blockIdx.x - NS) * 1024 + tid;             // 11*1024 = 88*128
    int s = tg >> 7, c = tg & 127;

    float wk3e[4], wk3o[6], wk2e[2], wk2o[2];
#pragma unroll
    for (int k = 0; k < 4; ++k) wk3e[k] = w3_0e[(s * 4 + k) * CCH + c];
#pragma unroll
    for (int k = 0; k < 6; ++k) wk3o[k] = w3_1o[(s * 6 + k) * CCH + c];
#pragma unroll
    for (int k = 0; k < 2; ++k) wk2e[k] = w2_0e[(s * 2 + k) * CCH + c];
#pragma unroll
    for (int k = 0; k < 2; ++k) wk2o[k] = w2_1o[(s * 2 + k) * CCH + c];
    float wk1e = w1_0e[s * CCH + c];
    float wk1o = w1_1o[s * CCH + c];

    f32x4* Trow = reinterpret_cast<f32x4*>(T) + (size_t)s * 34 * CCH + c;
#pragma unroll
    for (int m = 0; m < 20; ++m) {
        f32x4 row;
        float e = 0.f;
#pragma unroll
        for (int k = 0; k < 4; ++k) e = fmaf(S3e[m][k], wk3e[k], e);
        row.x = e;
#pragma unroll
        for (int i = 0; i < 3; ++i) {
            float o = 0.f;
#pragma unroll
            for (int k = 0; k < 6; ++k) o = fmaf(S3o[m][k][i], wk3o[k], o);
            row[1 + i] = o;
        }
        Trow[m * CCH] = row;
    }
#pragma unroll
    for (int m = 0; m < 10; ++m) {
        f32x4 row;
        row.x = fmaf(S2e[m][0], wk2e[0], S2e[m][1] * wk2e[1]);
#pragma unroll
        for (int i = 0; i < 3; ++i)
            row[1 + i] = fmaf(S2o[m][0][i], wk2o[0], S2o[m][1][i] * wk2o[1]);
        Trow[(20 + m) * CCH] = row;
    }
#pragma unroll
    for (int d = 0; d < 4; ++d) {
        f32x4 row;
        row.x = S1e[d] * wk1e;
#pragma unroll
        for (int i = 0; i < 3; ++i) row[1 + i] = S1o[d][i] * wk1o;
        Trow[(30 + d) * CCH] = row;
    }
}

// ---------------- main kernel: R12 inner loop + memcpy coef staging ----------------
// Grid (NS, STR, 2): species s, stripe (AB=128 atoms), channel half g. Block 256 = 4 waves.
// (256,1): no declared min-occupancy -> allocator uses up to 512 VGPR, NO SPILL
// (R7/R9/R13/R14 lesson: min_waves>=2 makes hipcc spill this state).
// LDS coefs staged by pure coalesced memcpy from precomputed T (A/B vs R12's inline build).
// Per m: one ds_read_b128 feeds 8 atoms x 4 comps; x double-buffered across rounds.

__global__ __launch_bounds__(256, 1) void k_main(
    const float* __restrict__ x, const float* __restrict__ T,
    const int* __restrict__ list, const int* __restrict__ counts,
    float* __restrict__ out) {
    int s = blockIdx.x;
    int cnt = counts[s];
    int t0 = (int)blockIdx.y * AB;
    if (t0 >= cnt) return;                      // block-uniform
    int g = blockIdx.z;
    int tid = threadIdx.x;
    int c64 = tid & 63, h = tid >> 6;
    int cg = g * 64 + c64;
    int nvalid = cnt - t0;

    __shared__ float coefs[34 * 64 * 4];        // 34,816 B
    __shared__ int bidx[AB];

    // stage coef slice: coalesced memcpy from T (L2/L3-resident)
    {
        const f32x4* gsrc = reinterpret_cast<const f32x4*>(T) + (size_t)s * 34 * CCH + g * 64;
        f32x4* ldst = reinterpret_cast<f32x4*>(coefs);
        for (int i = tid; i < 34 * 64; i += 256) {
            int m = i >> 6, cc = i & 63;
            ldst[i] = gsrc[(size_t)m * CCH + cc];
        }
    }
    if (tid < AB) {
        int tt = t0 + tid;
        bidx[tid] = list[s * BCAP + (tt < cnt ? tt : cnt - 1)];
    }
    __syncthreads();

    const f32x4* cfs = reinterpret_cast<const f32x4*>(coefs);

    constexpr int A3[20] = {0,0,0,0,0,0,0,0,0,0,1,1,1,1,1,1,2,2,2,3};
    constexpr int B3[20] = {0,0,0,0,1,1,1,2,2,3,1,1,1,2,2,3,2,2,3,3};
    constexpr int D3[20] = {0,1,2,3,1,2,3,2,3,3,1,2,3,2,3,3,2,3,3,3};
    constexpr int A2[10] = {0,0,0,0,1,1,1,2,2,3};
    constexpr int B2[10] = {0,1,2,3,1,2,3,2,3,3};

    auto load_round = [&](int r, f32x4* dst) {
#pragma unroll
        for (int j = 0; j < 8; ++j) {
            int pos = r * 32 + h * 8 + j;
            int n = bidx[pos];
            dst[j] = *reinterpret_cast<const f32x4*>(x + (size_t)n * 512 + cg * 4);
        }
    };

    auto do_round = [&](int r, const f32x4* xr) {
        float acc[8][4];
#pragma unroll
        for (int j = 0; j < 8; ++j)
#pragma unroll
            for (int k = 0; k < 4; ++k) acc[j][k] = 0.f;

#pragma unroll
        for (int m = 0; m < 34; ++m) {
            f32x4 cf = cfs[m * 64 + c64];
#pragma unroll
            for (int j = 0; j < 8; ++j) {
                float mono;
                if (m < 20)      mono = xr[j][A3[m]] * xr[j][B3[m]] * xr[j][D3[m]];
                else if (m < 30) mono = xr[j][A2[m - 20]] * xr[j][B2[m - 20]];
                else             mono = xr[j][m - 30];
                acc[j][0] = fmaf(cf[0], mono, acc[j][0]);
                acc[j][1] = fmaf(cf[1], mono, acc[j][1]);
                acc[j][2] = fmaf(cf[2], mono, acc[j][2]);
                acc[j][3] = fmaf(cf[3], mono, acc[j][3]);
            }
        }
#pragma unroll
        for (int j = 0; j < 8; ++j) {
            int pos = r * 32 + h * 8 + j;
            if (pos < nvalid) {
                int n = bidx[pos];
                float* orow = out + (size_t)n * 512;
                orow[cg] = acc[j][0];
                orow[CCH + 3 * cg + 0] = acc[j][1];
                orow[CCH + 3 * cg + 1] = acc[j][2];
                orow[CCH + 3 * cg + 2] = acc[j][3];
            }
        }
    };

    int R = min(4, (min(nvalid, AB) + 31) >> 5);
    f32x4 xA[8], xB[8];
    load_round(0, xA);
    if (R > 1) load_round(1, xB);
    do_round(0, xA);
    if (R > 1) {
        if (R > 2) load_round(2, xA);
        do_round(1, xB);
        if (R > 2) {
            if (R > 3) load_round(3, xB);
            do_round(2, xA);
            if (R > 3) do_round(3, xB);
        }
    }
}

// ---------------- launch ----------------

extern "C" void kernel_launch(void* const* d_in, const int* in_sizes, int n_in,
                              void* d_out, int out_size, void* d_ws, size_t ws_size,
                              hipStream_t stream) {
    const float* x     = (const float*)d_in[0];
    const float* u1_0e = (const float*)d_in[1];
    const float* w1_0e = (const float*)d_in[2];
    const float* u1_1o = (const float*)d_in[3];
    const float* w1_1o = (const float*)d_in[4];
    const float* u2_0e = (const float*)d_in[5];
    const float* w2_0e = (const float*)d_in[6];
    const float* u2_1o = (const float*)d_in[7];
    const float* w2_1o = (const float*)d_in[8];
    const float* u3_0e = (const float*)d_in[9];
    const float* w3_0e = (const float*)d_in[10];
    const float* u3_1o = (const float*)d_in[11];
    const float* w3_1o = (const float*)d_in[12];
    const int*   spec  = (const int*)d_in[13];
    int N = in_sizes[13];
    float* out = (float*)d_out;

    char* ws = (char*)d_ws;
    float* T      = (float*)ws;                              // NS*34*CCH*4 floats (6.13 MB)
    size_t tbytes = (size_t)NS * 34 * CCH * 4 * sizeof(float);
    int* list     = (int*)(ws + tbytes);                     // NS*BCAP ints
    int* counts   = list + (size_t)NS * BCAP;                // NS ints

    k_setup<<<NS + 11, 1024, 0, stream>>>(
        spec, N,
        u1_0e, w1_0e, u1_1o, w1_1o,
        u2_0e, w2_0e, u2_1o, w2_1o,
        u3_0e, w3_0e, u3_1o, w3_1o,
        T, counts, list);
    k_main<<<dim3(NS, STR, 2), 256, 0, stream>>>(x, T, list, counts, out);
}

// Round 16
// 43.366 us; speedup vs baseline: 7.0234x; 1.0832x over previous
//
#include <hip/hip_runtime.h>

#define NS    88     // species
#define CCH   128    // channels
#define BCAP  16384  // per-species bucket capacity
#define STR   16     // stripe blocks per species (16 atoms each; grid-stride beyond)

typedef float f32x4 __attribute__((ext_vector_type(4)));

__device__ const int TRI[20][3] = {
    {0,0,0},{0,0,1},{0,0,2},{0,0,3},{0,1,1},{0,1,2},{0,1,3},{0,2,2},{0,2,3},{0,3,3},
    {1,1,1},{1,1,2},{1,1,3},{1,2,2},{1,2,3},{1,3,3},
    {2,2,2},{2,2,3},{2,3,3},
    {3,3,3}};
__device__ const int PAIR[10][2] = {
    {0,0},{0,1},{0,2},{0,3},{1,1},{1,2},{1,3},{2,2},{2,3},{3,3}};

// ---------------- fused setup: blocks 0..87 sort, 88..98 coef table (R13..R15-verified) ----------------
// T[s][m(34)][c(128)][4]; m: 0..19 cubic (TRI), 20..29 pairs, 30..33 linear; comp[0]=0e,[1..3]=1o.

__global__ __launch_bounds__(1024) void k_setup(
    const int* __restrict__ species, int N,
    const float* __restrict__ u1_0e, const float* __restrict__ w1_0e,
    const float* __restrict__ u1_1o, const float* __restrict__ w1_1o,
    const float* __restrict__ u2_0e, const float* __restrict__ w2_0e,
    const float* __restrict__ u2_1o, const float* __restrict__ w2_1o,
    const float* __restrict__ u3_0e, const float* __restrict__ w3_0e,
    const float* __restrict__ u3_1o, const float* __restrict__ w3_1o,
    float* __restrict__ T, int* __restrict__ counts, int* __restrict__ list) {

    __shared__ int wh[16];
    __shared__ float S3e[20][4];
    __shared__ float S3o[20][6][3];
    __shared__ float S2e[10][2];
    __shared__ float S2o[10][2][3];
    __shared__ float S1e[4];
    __shared__ float S1o[4][3];

    int tid = threadIdx.x;

    if (blockIdx.x < NS) {
        int s = blockIdx.x;
        int lane = tid & 63, w = tid >> 6;
        int* bucket = list + s * BCAP;
        int pos = 0;
        for (int base = 0; base < N; base += 1024) {
            int n = base + tid;
            bool m = (n < N) && (species[n] == s);
            unsigned long long b = __ballot(m);
            int rank = __popcll(b & ((1ull << lane) - 1));
            if (lane == 0) wh[w] = __popcll(b);
            __syncthreads();
            int wbase = 0, tot = 0;
#pragma unroll
            for (int i = 0; i < 16; ++i) { int v = wh[i]; if (i < w) wbase += v; tot += v; }
            if (m) bucket[pos + wbase + rank] = n;
            pos += tot;
            __syncthreads();
        }
        if (tid == 0) counts[s] = pos;
        return;
    }

    // ---- stage A: symmetrized bases into LDS (536 jobs) ----
    for (int j = tid; j < 536; j += 1024) {
        if (j < 80) {
            int m = j >> 2, k = j & 3;
            int a = TRI[m][0], b = TRI[m][1], d = TRI[m][2];
            int P[6][3] = {{a,b,d},{a,d,b},{b,a,d},{b,d,a},{d,a,b},{d,b,a}};
            float acc = 0.f;
#pragma unroll
            for (int p = 0; p < 6; ++p)
                acc += u3_0e[((P[p][0] * 4 + P[p][1]) * 4 + P[p][2]) * 4 + k];
            float inv = (a == d) ? (1.f / 6.f) : ((a == b || b == d) ? 0.5f : 1.f);
            S3e[m][k] = acc * inv;
        } else if (j < 440) {
            int r = j - 80;
            int m = r / 18, jj = r % 18, k = jj / 3, i = jj % 3;
            int a = TRI[m][0], b = TRI[m][1], d = TRI[m][2];
            int P[6][3] = {{a,b,d},{a,d,b},{b,a,d},{b,d,a},{d,a,b},{d,b,a}};
            float acc = 0.f;
#pragma unroll
            for (int p = 0; p < 6; ++p)
                acc += u3_1o[(((P[p][0] * 4 + P[p][1]) * 4 + P[p][2]) * 6 + k) * 3 + i];
            float inv = (a == d) ? (1.f / 6.f) : ((a == b || b == d) ? 0.5f : 1.f);
            S3o[m][k][i] = acc * inv;
        } else if (j < 460) {
            int r = j - 440;
            int m = r >> 1, k = r & 1;
            int a = PAIR[m][0], b = PAIR[m][1];
            float acc = u2_0e[(a * 4 + b) * 2 + k];
            if (a != b) acc += u2_0e[(b * 4 + a) * 2 + k];
            S2e[m][k] = acc;
        } else if (j < 520) {
            int r = j - 460;
            int m = r / 6, jj = r % 6, k = jj / 3, i = jj % 3;
            int a = PAIR[m][0], b = PAIR[m][1];
            float acc = u2_1o[((a * 4 + b) * 2 + k) * 3 + i];
            if (a != b) acc += u2_1o[((b * 4 + a) * 2 + k) * 3 + i];
            S2o[m][k][i] = acc;
        } else if (j < 524) {
            int d = j - 520;
            S1e[d] = u1_0e[d];
        } else {
            int r = j - 524;
            S1o[r / 3][r % 3] = u1_1o[r];
        }
    }
    __syncthreads();

    // ---- stage B: per (s,c) contraction with weights -> T rows ----
    int tg = (blockIdx.x - NS) * 1024 + tid;             // 11*1024 = 88*128
    int s = tg >> 7, c = tg & 127;

    float wk3e[4], wk3o[6], wk2e[2], wk2o[2];
#pragma unroll
    for (int k = 0; k < 4; ++k) wk3e[k] = w3_0e[(s * 4 + k) * CCH + c];
#pragma unroll
    for (int k = 0; k < 6; ++k) wk3o[k] = w3_1o[(s * 6 + k) * CCH + c];
#pragma unroll
    for (int k = 0; k < 2; ++k) wk2e[k] = w2_0e[(s * 2 + k) * CCH + c];
#pragma unroll
    for (int k = 0; k < 2; ++k) wk2o[k] = w2_1o[(s * 2 + k) * CCH + c];
    float wk1e = w1_0e[s * CCH + c];
    float wk1o = w1_1o[s * CCH + c];

    f32x4* Trow = reinterpret_cast<f32x4*>(T) + (size_t)s * 34 * CCH + c;
#pragma unroll
    for (int m = 0; m < 20; ++m) {
        f32x4 row;
        float e = 0.f;
#pragma unroll
        for (int k = 0; k < 4; ++k) e = fmaf(S3e[m][k], wk3e[k], e);
        row.x = e;
#pragma unroll
        for (int i = 0; i < 3; ++i) {
            float o = 0.f;
#pragma unroll
            for (int k = 0; k < 6; ++k) o = fmaf(S3o[m][k][i], wk3o[k], o);
            row[1 + i] = o;
        }
        Trow[m * CCH] = row;
    }
#pragma unroll
    for (int m = 0; m < 10; ++m) {
        f32x4 row;
        row.x = fmaf(S2e[m][0], wk2e[0], S2e[m][1] * wk2e[1]);
#pragma unroll
        for (int i = 0; i < 3; ++i)
            row[1 + i] = fmaf(S2o[m][0][i], wk2o[0], S2o[m][1][i] * wk2o[1]);
        Trow[(20 + m) * CCH] = row;
    }
#pragma unroll
    for (int d = 0; d < 4; ++d) {
        f32x4 row;
        row.x = S1e[d] * wk1e;
#pragma unroll
        for (int i = 0; i < 3; ++i) row[1 + i] = S1o[d][i] * wk1o;
        Trow[(30 + d) * CCH] = row;
    }
}

// ---------------- main kernel: small state, LDS coefs, NATURAL allocation ----------------
// Identical to R14 except __launch_bounds__(256, 1): the allocator spills whenever
// min_waves>=2 is declared (R7:120, R9:96, R13:84, R14:64 — all spilled); with
// min_waves=1 it never spills (R10, R12, R15). State ~55 floats -> expect <=128 VGPR
// and 4+ waves/SIMD naturally. Grid (NS, STR, 2): ~2100 blocks, ~8400 waves.

__global__ __launch_bounds__(256, 1) void k_main(
    const float* __restrict__ x, const float* __restrict__ T,
    const int* __restrict__ list, const int* __restrict__ counts,
    float* __restrict__ out) {
    int s = blockIdx.x;
    int cnt = counts[s];
    if ((int)blockIdx.y * 16 >= cnt) return;    // block-uniform
    int g = blockIdx.z;
    int tid = threadIdx.x;
    int c64 = tid & 63, grp = tid >> 6;
    int cg = g * 64 + c64;
    const int* bucket = list + s * BCAP;

    __shared__ float coefs[34 * 64 * 4];        // 34,816 B
    __shared__ int bidx[16];

    // stage coef slice (coalesced 1KB runs from T, L2/L3-resident)
    {
        const f32x4* gsrc = reinterpret_cast<const f32x4*>(T) + (size_t)s * 34 * CCH + g * 64;
        f32x4* ldst = reinterpret_cast<f32x4*>(coefs);
        for (int i = tid; i < 34 * 64; i += 256) {
            int m = i >> 6, cc = i & 63;
            ldst[i] = gsrc[(size_t)m * CCH + cc];
        }
    }
    const f32x4* cfs = reinterpret_cast<const f32x4*>(coefs);

    constexpr int A3[20] = {0,0,0,0,0,0,0,0,0,0,1,1,1,1,1,1,2,2,2,3};
    constexpr int B3[20] = {0,0,0,0,1,1,1,2,2,3,1,1,1,2,2,3,2,2,3,3};
    constexpr int D3[20] = {0,1,2,3,1,2,3,2,3,3,1,2,3,2,3,3,2,3,3,3};
    constexpr int A2[10] = {0,0,0,0,1,1,1,2,2,3};
    constexpr int B2[10] = {0,1,2,3,1,2,3,2,3,3};

    for (int t0 = (int)blockIdx.y * 16; t0 < cnt; t0 += STR * 16) {
        if (tid < 16) {
            int tt = t0 + tid;
            bidx[tid] = bucket[tt < cnt ? tt : cnt - 1];
        }
        __syncthreads();
        int nvalid = cnt - t0;

        int nn[4];
        f32x4 xr[4];
#pragma unroll
        for (int j = 0; j < 4; ++j) {
            nn[j] = bidx[grp * 4 + j];
            xr[j] = *reinterpret_cast<const f32x4*>(x + (size_t)nn[j] * 512 + cg * 4);
        }

        float acc[4][4];
#pragma unroll
        for (int j = 0; j < 4; ++j)
#pragma unroll
            for (int k = 0; k < 4; ++k) acc[j][k] = 0.f;

#pragma unroll
        for (int m = 0; m < 34; ++m) {
            f32x4 cf = cfs[m * 64 + c64];
#pragma unroll
            for (int j = 0; j < 4; ++j) {
                float mono;
                if (m < 20)      mono = xr[j][A3[m]] * xr[j][B3[m]] * xr[j][D3[m]];
                else if (m < 30) mono = xr[j][A2[m - 20]] * xr[j][B2[m - 20]];
                else             mono = xr[j][m - 30];
                acc[j][0] = fmaf(cf[0], mono, acc[j][0]);
                acc[j][1] = fmaf(cf[1], mono, acc[j][1]);
                acc[j][2] = fmaf(cf[2], mono, acc[j][2]);
                acc[j][3] = fmaf(cf[3], mono, acc[j][3]);
            }
        }

#pragma unroll
        for (int j = 0; j < 4; ++j) {
            if (grp * 4 + j < nvalid) {
                float* orow = out + (size_t)nn[j] * 512;
                orow[cg] = acc[j][0];
                orow[CCH + 3 * cg + 0] = acc[j][1];
                orow[CCH + 3 * cg + 1] = acc[j][2];
                orow[CCH + 3 * cg + 2] = acc[j][3];
            }
        }
        __syncthreads();
    }
}

// ---------------- launch ----------------

extern "C" void kernel_launch(void* const* d_in, const int* in_sizes, int n_in,
                              void* d_out, int out_size, void* d_ws, size_t ws_size,
                              hipStream_t stream) {
    const float* x     = (const float*)d_in[0];
    const float* u1_0e = (const float*)d_in[1];
    const float* w1_0e = (const float*)d_in[2];
    const float* u1_1o = (const float*)d_in[3];
    const float* w1_1o = (const float*)d_in[4];
    const float* u2_0e = (const float*)d_in[5];
    const float* w2_0e = (const float*)d_in[6];
    const float* u2_1o = (const float*)d_in[7];
    const float* w2_1o = (const float*)d_in[8];
    const float* u3_0e = (const float*)d_in[9];
    const float* w3_0e = (const float*)d_in[10];
    const float* u3_1o = (const float*)d_in[11];
    const float* w3_1o = (const float*)d_in[12];
    const int*   spec  = (const int*)d_in[13];
    int N = in_sizes[13];
    float* out = (float*)d_out;

    char* ws = (char*)d_ws;
    float* T      = (float*)ws;                              // NS*34*CCH*4 floats (6.13 MB)
    size_t tbytes = (size_t)NS * 34 * CCH * 4 * sizeof(float);
    int* list     = (int*)(ws + tbytes);                     // NS*BCAP ints
    int* counts   = list + (size_t)NS * BCAP;                // NS ints

    k_setup<<<NS + 11, 1024, 0, stream>>>(
        spec, N,
        u1_0e, w1_0e, u1_1o, w1_1o,
        u2_0e, w2_0e, u2_1o, w2_1o,
        u3_0e, w3_0e, u3_1o, w3_1o,
        T, counts, list);
    k_main<<<dim3(NS, STR, 2), 256, 0, stream>>>(x, T, list, counts, out);
}